// Round 1
// baseline (391.616 us; speedup 1.0000x reference)
//
#include <hip/hip_runtime.h>
#include <hip/hip_bf16.h>
#include <stdint.h>

// GatedScreeningTile: B=2 N=2048 DIM=2048 H=16 DK=64 DV=128 DIM_INNER=3072
// Pipeline: cvt/transpose -> GEMM(qg) GEMM(kv) -> normalize -> fused screened-attention -> GEMM(out)

typedef unsigned short u16;
typedef __bf16 bf16x8 __attribute__((ext_vector_type(8)));
typedef u16 u16x8 __attribute__((ext_vector_type(8)));
typedef float f32x4 __attribute__((ext_vector_type(4)));

#define DEVINL __device__ __forceinline__

DEVINL u16 f2bf(float f) {
  union { float f; uint32_t u; } v; v.f = f;
  uint32_t r = (v.u + 0x7FFFu + ((v.u >> 16) & 1u)) >> 16;
  return (u16)r;
}
DEVINL float bf2f(u16 x) {
  union { uint32_t u; float f; } v; v.u = ((uint32_t)x) << 16;
  return v.f;
}
DEVINL bf16x8 as_bf(u16x8 v) { return __builtin_bit_cast(bf16x8, v); }

typedef const __attribute__((address_space(1))) uint32_t* gptr_t;
typedef __attribute__((address_space(3))) uint32_t* lptr_t;
DEVINL void gload_lds16(const void* g, void* l) {
  __builtin_amdgcn_global_load_lds((gptr_t)g, (lptr_t)l, 16, 0, 0);
}

DEVINL f32x4 mfma16(u16x8 a, u16x8 b, f32x4 c) {
  return __builtin_amdgcn_mfma_f32_16x16x32_bf16(as_bf(a), as_bf(b), c, 0, 0, 0);
}

// ---------------- fp32 -> bf16 convert (same layout) ----------------
__global__ void k_cvt(const float* __restrict__ src, u16* __restrict__ dst, int n) {
  int i = (blockIdx.x * blockDim.x + threadIdx.x) * 4;
  int stride = gridDim.x * blockDim.x * 4;
  for (; i < n; i += stride) {
    float4 f = *(const float4*)(src + i);
    ushort4 o;
    o.x = f2bf(f.x); o.y = f2bf(f.y); o.z = f2bf(f.z); o.w = f2bf(f.w);
    *(ushort4*)(dst + i) = o;
  }
}

// ---------------- fp32 (RxC) -> bf16 transposed (CxR) ----------------
__global__ void k_cvtT(const float* __restrict__ src, u16* __restrict__ dst, int R, int C) {
  __shared__ float tile[32][33];
  int c0 = blockIdx.x * 32, r0 = blockIdx.y * 32;
  int tc = threadIdx.x & 31, tr = threadIdx.x >> 5;  // tr 0..7
#pragma unroll
  for (int i = 0; i < 4; i++) {
    int r = tr + i * 8;
    tile[r][tc] = src[(size_t)(r0 + r) * C + c0 + tc];
  }
  __syncthreads();
#pragma unroll
  for (int i = 0; i < 4; i++) {
    int r = tr + i * 8;  // row in dst tile (= src col)
    dst[(size_t)(c0 + r) * R + r0 + tc] = f2bf(tile[tc][r]);
  }
}

// ---------------- bf16 GEMM: C(MxNt) = A(MxK,row-major) * Bt(NtxK,row-major)^T ----------------
// 128x128 tile, BK=32, 4 waves (2x2), 16x16x32 MFMA, global_load_lds staging.
template <int F32OUT>
__global__ __launch_bounds__(256, 2) void k_gemm(const u16* __restrict__ A,
                                                 const u16* __restrict__ Bt,
                                                 void* __restrict__ Cout,
                                                 int M, int Nt, int K) {
  __shared__ u16 As[128 * 32];
  __shared__ u16 Bs[128 * 32];
  const int tid = threadIdx.x, lane = tid & 63, wid = tid >> 6;
  const int m0 = blockIdx.y * 128, n0 = blockIdx.x * 128;
  const int wm = (wid >> 1) * 64, wn = (wid & 1) * 64;
  const int fr = lane & 15, fc = (lane >> 4) * 8;

  f32x4 acc[4][4] = {};

  // staging: wave wid covers rows [wid*32, wid*32+32), 2 insts of 1KB each
  const u16* gA = A + (size_t)(m0 + wid * 32 + (lane >> 2)) * K + (lane & 3) * 8;
  const u16* gB = Bt + (size_t)(n0 + wid * 32 + (lane >> 2)) * K + (lane & 3) * 8;
  u16* lA = As + wid * 1024;
  u16* lB = Bs + wid * 1024;
  const size_t rowskip = (size_t)16 * K;

  for (int k0 = 0; k0 < K; k0 += 32) {
    gload_lds16(gA + k0, lA);
    gload_lds16(gA + k0 + rowskip, lA + 512);
    gload_lds16(gB + k0, lB);
    gload_lds16(gB + k0 + rowskip, lB + 512);
    __syncthreads();
    u16x8 a[4], b[4];
#pragma unroll
    for (int mi = 0; mi < 4; mi++) a[mi] = *(const u16x8*)(As + (wm + mi * 16 + fr) * 32 + fc);
#pragma unroll
    for (int ni = 0; ni < 4; ni++) b[ni] = *(const u16x8*)(Bs + (wn + ni * 16 + fr) * 32 + fc);
#pragma unroll
    for (int mi = 0; mi < 4; mi++)
#pragma unroll
      for (int ni = 0; ni < 4; ni++)
        acc[mi][ni] = mfma16(a[mi], b[ni], acc[mi][ni]);
    __syncthreads();
  }

  const int frow = (lane >> 4) * 4;
#pragma unroll
  for (int mi = 0; mi < 4; mi++)
#pragma unroll
    for (int ni = 0; ni < 4; ni++)
#pragma unroll
      for (int j = 0; j < 4; j++) {
        const size_t row = m0 + wm + mi * 16 + frow + j;
        const size_t col = n0 + wn + ni * 16 + fr;
        if (F32OUT) ((float*)Cout)[row * Nt + col] = acc[mi][ni][j];
        else ((u16*)Cout)[row * Nt + col] = f2bf(acc[mi][ni][j]);
      }
}

// ---------------- normalize: qg/kv raw -> qn, kn, vnT, gact ----------------
// one wave per (b,n,h)
__global__ __launch_bounds__(256, 4) void k_norm(const u16* __restrict__ qg,
                                                 const u16* __restrict__ kv,
                                                 u16* __restrict__ qn, u16* __restrict__ kn,
                                                 u16* __restrict__ vnT, u16* __restrict__ gact) {
  const int tid = threadIdx.x, lane = tid & 63, wid = tid >> 6;
  const int idx = blockIdx.x * 4 + wid;  // (b*N+n)*H + h
  const int h = idx & 15;
  const int bn = idx >> 4;      // b*N + n
  const int n = bn & 2047;
  const int b = bn >> 11;
  const size_t base = (size_t)bn * 3072 + h * 192;

  float q = bf2f(qg[base + lane]);
  float g0 = bf2f(qg[base + 64 + lane]);
  float g1 = bf2f(qg[base + 128 + lane]);
  float k = bf2f(kv[base + lane]);
  float v0 = bf2f(kv[base + 64 + lane]);
  float v1 = bf2f(kv[base + 128 + lane]);

  float qs = q * q, ks = k * k, vs = v0 * v0 + v1 * v1;
#pragma unroll
  for (int m = 1; m < 64; m <<= 1) {
    qs += __shfl_xor(qs, m);
    ks += __shfl_xor(ks, m);
    vs += __shfl_xor(vs, m);
  }
  float rq = 1.f / fmaxf(sqrtf(qs), 1e-12f);
  float rk = 1.f / fmaxf(sqrtf(ks), 1e-12f);
  float rv = 1.f / fmaxf(sqrtf(vs), 1e-12f);

  const size_t hb = (size_t)(b * 16 + h);
  qn[(hb * 2048 + n) * 64 + lane] = f2bf(q * rq);
  kn[(hb * 2048 + n) * 64 + lane] = f2bf(k * rk);
  vnT[(hb * 128 + lane) * 2048 + n] = f2bf(v0 * rv);
  vnT[(hb * 128 + 64 + lane) * 2048 + n] = f2bf(v1 * rv);
  float s0 = g0 / (1.f + __expf(-g0));
  float s1 = g1 / (1.f + __expf(-g1));
  gact[(hb * 2048 + n) * 128 + lane] = f2bf(tanhf(s0));
  gact[(hb * 2048 + n) * 128 + 64 + lane] = f2bf(tanhf(s1));
}

// ---------------- fused screened attention ----------------
// grid (N/128, B*H), 256 threads (4 waves 2x2). Q in regs; K,VT,P in LDS.
__global__ __launch_bounds__(256, 1) void k_attn(const u16* __restrict__ qn,
                                                 const u16* __restrict__ kn,
                                                 const u16* __restrict__ vnT,
                                                 const u16* __restrict__ gact,
                                                 const float* __restrict__ ls_iaw,
                                                 const float* __restrict__ ls_hws,
                                                 u16* __restrict__ pre_out) {
  extern __shared__ char smem[];
  u16* Ks = (u16*)smem;                  // [128][64]
  u16* Vs = (u16*)(smem + 16384);        // [128 d][128 n]
  u16* Ps = (u16*)(smem + 49152);        // [128][136] padded
  float* nbuf = (float*)(smem + 49152);  // reuse after loop: [2][128]

  const int tid = threadIdx.x, lane = tid & 63, wid = tid >> 6;
  const int bh = blockIdx.y, h = bh & 15;
  const int n0 = blockIdx.x * 128;
  const int wq = (wid >> 1) * 64, wc = (wid & 1) * 64;
  const float r = 1.f / (__expf(ls_iaw[h]) + 1.f);
  const float whs = __expf(ls_hws[h]);
  const int fr = lane & 15, fc = (lane >> 4) * 8, frow = (lane >> 4) * 4;

  // Q fragments in registers (reused across all KV tiles)
  const u16* qbase = qn + ((size_t)bh * 2048 + n0) * 64;
  u16x8 qf[4][2];
#pragma unroll
  for (int mi = 0; mi < 4; mi++)
#pragma unroll
    for (int kk = 0; kk < 2; kk++)
      qf[mi][kk] = *(const u16x8*)(qbase + (wq + mi * 16 + fr) * 64 + kk * 32 + fc);

  f32x4 acc[4][4] = {};
  const u16* kbase = kn + (size_t)bh * 2048 * 64;
  const u16* vbase = vnT + (size_t)bh * 128 * 2048;

  const int krow = wid * 32 + (lane >> 3), kcol = (lane & 7) * 8;
  const int vrow = wid * 32 + (lane >> 4), vcol = fr * 8;

  for (int t = 0; t < 16; t++) {
    const int kv0 = t * 128;
#pragma unroll
    for (int i = 0; i < 4; i++)
      gload_lds16(kbase + (size_t)(kv0 + krow + i * 8) * 64 + kcol, Ks + wid * 2048 + i * 512);
#pragma unroll
    for (int i = 0; i < 8; i++)
      gload_lds16(vbase + (size_t)(vrow + i * 4) * 2048 + kv0 + vcol, Vs + wid * 4096 + i * 512);
    __syncthreads();

    // sim = q @ k^T for this wave's (wq, wc=kv-block)
    f32x4 s[4][4] = {};
#pragma unroll
    for (int kk = 0; kk < 2; kk++) {
      u16x8 kf[4];
#pragma unroll
      for (int ni = 0; ni < 4; ni++)
        kf[ni] = *(const u16x8*)(Ks + (wc + ni * 16 + fr) * 64 + kk * 32 + fc);
#pragma unroll
      for (int mi = 0; mi < 4; mi++)
#pragma unroll
        for (int ni = 0; ni < 4; ni++)
          s[mi][ni] = mfma16(qf[mi][kk], kf[ni], s[mi][ni]);
    }
    // screen + write P to LDS
#pragma unroll
    for (int mi = 0; mi < 4; mi++)
#pragma unroll
      for (int ni = 0; ni < 4; ni++)
#pragma unroll
        for (int j = 0; j < 4; j++) {
          float p = fmaxf(0.f, 1.f - r * (1.f - s[mi][ni][j]));
          Ps[(wq + mi * 16 + frow + j) * 136 + wc + ni * 16 + fr] = f2bf(p * p);
        }
    __syncthreads();

    // PV: acc += P @ V  (wc = this wave's d-block)
#pragma unroll
    for (int kk = 0; kk < 4; kk++) {
      u16x8 pf[4], vf[4];
#pragma unroll
      for (int mi = 0; mi < 4; mi++)
        pf[mi] = *(const u16x8*)(Ps + (wq + mi * 16 + fr) * 136 + kk * 32 + fc);
#pragma unroll
      for (int ni = 0; ni < 4; ni++)
        vf[ni] = *(const u16x8*)(Vs + (wc + ni * 16 + fr) * 128 + kk * 32 + fc);
#pragma unroll
      for (int mi = 0; mi < 4; mi++)
#pragma unroll
        for (int ni = 0; ni < 4; ni++)
          acc[mi][ni] = mfma16(pf[mi], vf[ni], acc[mi][ni]);
    }
    __syncthreads();
  }

  // epilogue: tanh_norm(aggr) * gact * exp(ls_hws) -> pre_out[(b*N+n)][h*128+d]
#pragma unroll
  for (int mi = 0; mi < 4; mi++)
#pragma unroll
    for (int j = 0; j < 4; j++) {
      float ss = 0.f;
#pragma unroll
      for (int ni = 0; ni < 4; ni++) { float x = acc[mi][ni][j]; ss += x * x; }
#pragma unroll
      for (int m = 1; m < 16; m <<= 1) ss += __shfl_xor(ss, m);
      if (fr == 0) nbuf[(wid & 1) * 128 + wq + mi * 16 + frow + j] = ss;
    }
  __syncthreads();

  const size_t gbase = ((size_t)bh * 2048 + n0) * 128;
  const size_t obase = ((size_t)(bh >> 4) * 2048 + n0);
#pragma unroll
  for (int mi = 0; mi < 4; mi++)
#pragma unroll
    for (int j = 0; j < 4; j++) {
      const int row = wq + mi * 16 + frow + j;
      float nsq = nbuf[row] + nbuf[128 + row];
      float nn = sqrtf(nsq);
      float scale = tanhf(nn) / fmaxf(nn, 1e-12f) * whs;
#pragma unroll
      for (int ni = 0; ni < 4; ni++) {
        const int d = wc + ni * 16 + fr;
        float gv = bf2f(gact[gbase + (size_t)row * 128 + d]);
        pre_out[(obase + row) * 2048 + h * 128 + d] = f2bf(acc[mi][ni][j] * scale * gv);
      }
    }
}

extern "C" void kernel_launch(void* const* d_in, const int* in_sizes, int n_in,
                              void* d_out, int out_size, void* d_ws, size_t ws_size,
                              hipStream_t stream) {
  (void)in_sizes; (void)n_in; (void)out_size; (void)ws_size;
  const float* tokens = (const float*)d_in[0];
  const float* Wqg = (const float*)d_in[1];
  const float* Wkv = (const float*)d_in[2];
  const float* Wo = (const float*)d_in[3];
  const float* ls_iaw = (const float*)d_in[4];
  const float* ls_hws = (const float*)d_in[5];
  float* out = (float*)d_out;
  char* ws = (char*)d_ws;

  // workspace layout (phased aliasing, total 104 MB):
  u16* WoT = (u16*)(ws + 0);                     // 8,388,608 B
  char* regA = ws + 8388608;                     // 50,331,648 B
  u16* tok_bf = (u16*)(regA);                    // phase A-B
  u16* WqgT = (u16*)(regA + 16777216);
  u16* WkvT = (u16*)(regA + 29360128);
  u16* qn = (u16*)(regA);                        // phase C-D
  u16* kn = (u16*)(regA + 8388608);
  u16* vnT = (u16*)(regA + 16777216);
  u16* gact = (u16*)(regA + 33554432);
  char* regB = ws + 58720256;                    // 50,331,648 B
  u16* qg_raw = (u16*)(regB);                    // phase B-C
  u16* kv_raw = (u16*)(regB + 25165824);
  u16* pre_out = (u16*)(regB);                   // phase D-E

  k_cvt<<<4096, 256, 0, stream>>>(tokens, tok_bf, 8388608);
  k_cvtT<<<dim3(96, 64), 256, 0, stream>>>(Wqg, WqgT, 2048, 3072);
  k_cvtT<<<dim3(96, 64), 256, 0, stream>>>(Wkv, WkvT, 2048, 3072);
  k_cvtT<<<dim3(64, 64), 256, 0, stream>>>(Wo, WoT, 2048, 2048);

  k_gemm<0><<<dim3(24, 32), 256, 0, stream>>>(tok_bf, WqgT, qg_raw, 4096, 3072, 2048);
  k_gemm<0><<<dim3(24, 32), 256, 0, stream>>>(tok_bf, WkvT, kv_raw, 4096, 3072, 2048);

  k_norm<<<16384, 256, 0, stream>>>(qg_raw, kv_raw, qn, kn, vnT, gact);

  k_attn<<<dim3(16, 32), 256, 83968, stream>>>(qn, kn, vnT, gact, ls_iaw, ls_hws, pre_out);

  k_gemm<1><<<dim3(16, 32), 256, 0, stream>>>(pre_out, WoT, out, 4096, 2048, 2048);
}

// Round 2
// 346.053 us; speedup vs baseline: 1.1317x; 1.1317x over previous
//
#include <hip/hip_runtime.h>
#include <hip/hip_bf16.h>
#include <stdint.h>

// GatedScreeningTile: B=2 N=2048 DIM=2048 H=16 DK=64 DV=128 DIM_INNER=3072
// Pipeline: cvt/transpose -> GEMM(qg) GEMM(kv) -> normalize -> fused screened-attention -> GEMM(out)

typedef unsigned short u16;
typedef __bf16 bf16x8 __attribute__((ext_vector_type(8)));
typedef u16 u16x8 __attribute__((ext_vector_type(8)));
typedef float f32x4 __attribute__((ext_vector_type(4)));

#define DEVINL __device__ __forceinline__

DEVINL u16 f2bf(float f) {
  union { float f; uint32_t u; } v; v.f = f;
  uint32_t r = (v.u + 0x7FFFu + ((v.u >> 16) & 1u)) >> 16;
  return (u16)r;
}
DEVINL float bf2f(u16 x) {
  union { uint32_t u; float f; } v; v.u = ((uint32_t)x) << 16;
  return v.f;
}
DEVINL bf16x8 as_bf(u16x8 v) { return __builtin_bit_cast(bf16x8, v); }

typedef const __attribute__((address_space(1))) uint32_t* gptr_t;
typedef __attribute__((address_space(3))) uint32_t* lptr_t;
DEVINL void gload_lds16(const void* g, void* l) {
  __builtin_amdgcn_global_load_lds((gptr_t)g, (lptr_t)l, 16, 0, 0);
}

DEVINL f32x4 mfma16(u16x8 a, u16x8 b, f32x4 c) {
  return __builtin_amdgcn_mfma_f32_16x16x32_bf16(as_bf(a), as_bf(b), c, 0, 0, 0);
}

// ---------------- fp32 -> bf16 convert (same layout) ----------------
__global__ void k_cvt(const float* __restrict__ src, u16* __restrict__ dst, int n) {
  int i = (blockIdx.x * blockDim.x + threadIdx.x) * 4;
  int stride = gridDim.x * blockDim.x * 4;
  for (; i < n; i += stride) {
    float4 f = *(const float4*)(src + i);
    ushort4 o;
    o.x = f2bf(f.x); o.y = f2bf(f.y); o.z = f2bf(f.z); o.w = f2bf(f.w);
    *(ushort4*)(dst + i) = o;
  }
}

// ---------------- fp32 (RxC) -> bf16 transposed (CxR) ----------------
__global__ void k_cvtT(const float* __restrict__ src, u16* __restrict__ dst, int R, int C) {
  __shared__ float tile[32][33];
  int c0 = blockIdx.x * 32, r0 = blockIdx.y * 32;
  int tc = threadIdx.x & 31, tr = threadIdx.x >> 5;  // tr 0..7
#pragma unroll
  for (int i = 0; i < 4; i++) {
    int r = tr + i * 8;
    tile[r][tc] = src[(size_t)(r0 + r) * C + c0 + tc];
  }
  __syncthreads();
#pragma unroll
  for (int i = 0; i < 4; i++) {
    int r = tr + i * 8;  // row in dst tile (= src col)
    dst[(size_t)(c0 + r) * R + r0 + tc] = f2bf(tile[tc][r]);
  }
}

// ---------------- bf16 GEMM: C(MxNt) = A(MxK,row-major) * Bt(NtxK,row-major)^T ----------------
// 128x128 tile, BK=32, 4 waves (2x2), 16x16x32 MFMA, global_load_lds staging.
template <int F32OUT>
__global__ __launch_bounds__(256, 2) void k_gemm(const u16* __restrict__ A,
                                                 const u16* __restrict__ Bt,
                                                 void* __restrict__ Cout,
                                                 int M, int Nt, int K) {
  __shared__ u16 As[128 * 32];
  __shared__ u16 Bs[128 * 32];
  const int tid = threadIdx.x, lane = tid & 63, wid = tid >> 6;
  const int m0 = blockIdx.y * 128, n0 = blockIdx.x * 128;
  const int wm = (wid >> 1) * 64, wn = (wid & 1) * 64;
  const int fr = lane & 15, fc = (lane >> 4) * 8;

  f32x4 acc[4][4] = {};

  // staging: wave wid covers rows [wid*32, wid*32+32), 2 insts of 1KB each
  const u16* gA = A + (size_t)(m0 + wid * 32 + (lane >> 2)) * K + (lane & 3) * 8;
  const u16* gB = Bt + (size_t)(n0 + wid * 32 + (lane >> 2)) * K + (lane & 3) * 8;
  u16* lA = As + wid * 1024;
  u16* lB = Bs + wid * 1024;
  const size_t rowskip = (size_t)16 * K;

  for (int k0 = 0; k0 < K; k0 += 32) {
    gload_lds16(gA + k0, lA);
    gload_lds16(gA + k0 + rowskip, lA + 512);
    gload_lds16(gB + k0, lB);
    gload_lds16(gB + k0 + rowskip, lB + 512);
    __syncthreads();
    u16x8 a[4], b[4];
#pragma unroll
    for (int mi = 0; mi < 4; mi++) a[mi] = *(const u16x8*)(As + (wm + mi * 16 + fr) * 32 + fc);
#pragma unroll
    for (int ni = 0; ni < 4; ni++) b[ni] = *(const u16x8*)(Bs + (wn + ni * 16 + fr) * 32 + fc);
#pragma unroll
    for (int mi = 0; mi < 4; mi++)
#pragma unroll
      for (int ni = 0; ni < 4; ni++)
        acc[mi][ni] = mfma16(a[mi], b[ni], acc[mi][ni]);
    __syncthreads();
  }

  const int frow = (lane >> 4) * 4;
#pragma unroll
  for (int mi = 0; mi < 4; mi++)
#pragma unroll
    for (int ni = 0; ni < 4; ni++)
#pragma unroll
      for (int j = 0; j < 4; j++) {
        const size_t row = m0 + wm + mi * 16 + frow + j;
        const size_t col = n0 + wn + ni * 16 + fr;
        if (F32OUT) ((float*)Cout)[row * Nt + col] = acc[mi][ni][j];
        else ((u16*)Cout)[row * Nt + col] = f2bf(acc[mi][ni][j]);
      }
}

// ---------------- normalize: qg/kv raw -> qn, kn, vnT, gact ----------------
// one wave per (b,n,h)
__global__ __launch_bounds__(256, 4) void k_norm(const u16* __restrict__ qg,
                                                 const u16* __restrict__ kv,
                                                 u16* __restrict__ qn, u16* __restrict__ kn,
                                                 u16* __restrict__ vnT, u16* __restrict__ gact) {
  const int tid = threadIdx.x, lane = tid & 63, wid = tid >> 6;
  const int idx = blockIdx.x * 4 + wid;  // (b*N+n)*H + h
  const int h = idx & 15;
  const int bn = idx >> 4;      // b*N + n
  const int n = bn & 2047;
  const int b = bn >> 11;
  const size_t base = (size_t)bn * 3072 + h * 192;

  float q = bf2f(qg[base + lane]);
  float g0 = bf2f(qg[base + 64 + lane]);
  float g1 = bf2f(qg[base + 128 + lane]);
  float k = bf2f(kv[base + lane]);
  float v0 = bf2f(kv[base + 64 + lane]);
  float v1 = bf2f(kv[base + 128 + lane]);

  float qs = q * q, ks = k * k, vs = v0 * v0 + v1 * v1;
#pragma unroll
  for (int m = 1; m < 64; m <<= 1) {
    qs += __shfl_xor(qs, m);
    ks += __shfl_xor(ks, m);
    vs += __shfl_xor(vs, m);
  }
  float rq = 1.f / fmaxf(sqrtf(qs), 1e-12f);
  float rk = 1.f / fmaxf(sqrtf(ks), 1e-12f);
  float rv = 1.f / fmaxf(sqrtf(vs), 1e-12f);

  const size_t hb = (size_t)(b * 16 + h);
  qn[(hb * 2048 + n) * 64 + lane] = f2bf(q * rq);
  kn[(hb * 2048 + n) * 64 + lane] = f2bf(k * rk);
  vnT[(hb * 128 + lane) * 2048 + n] = f2bf(v0 * rv);
  vnT[(hb * 128 + 64 + lane) * 2048 + n] = f2bf(v1 * rv);
  float s0 = g0 / (1.f + __expf(-g0));
  float s1 = g1 / (1.f + __expf(-g1));
  gact[(hb * 2048 + n) * 128 + lane] = f2bf(tanhf(s0));
  gact[(hb * 2048 + n) * 128 + 64 + lane] = f2bf(tanhf(s1));
}

// ---------------- fused screened attention ----------------
// grid (N/128, B*H), 256 threads (4 waves 2x2). Q in regs; K,VT,P in LDS.
// All LDS tiles XOR-swizzled (16B-chunk ^ (row&7)); K/V staged via global_load_lds
// with INVERSE swizzle applied on the per-lane global source (linear LDS dest).
// LDS = 16K(Ks) + 32K(Vs) + 32K(Ps) = 80KB -> 2 blocks/CU (512 blocks = 2/CU exact).
__global__ __launch_bounds__(256, 2) void k_attn(const u16* __restrict__ qn,
                                                 const u16* __restrict__ kn,
                                                 const u16* __restrict__ vnT,
                                                 const u16* __restrict__ gact,
                                                 const float* __restrict__ ls_iaw,
                                                 const float* __restrict__ ls_hws,
                                                 u16* __restrict__ pre_out) {
  extern __shared__ char smem[];
  u16* Ks = (u16*)smem;                  // [128 k][64 dk]  rows 128B, 8 chunks, swizzled
  u16* Vs = (u16*)(smem + 16384);        // [128 d][128 k]  rows 256B, 16 chunks, swizzled
  u16* Ps = (u16*)(smem + 49152);        // [128 q][128 k]  rows 256B, swizzled
  float* nbuf = (float*)(smem + 49152);  // reuse after loop: [2][128]

  const int tid = threadIdx.x, lane = tid & 63, wid = tid >> 6;
  const int bh = blockIdx.y, h = bh & 15;
  const int n0 = blockIdx.x * 128;
  const int wq = (wid >> 1) * 64, wc = (wid & 1) * 64;
  const float r = 1.f / (__expf(ls_iaw[h]) + 1.f);
  const float whs = __expf(ls_hws[h]);
  const int fr = lane & 15, hi = lane >> 4, fc = hi * 8, frow = hi * 4;
  const int rb = fr & 7;  // row&7 for fragment rows (wq/wc/ni*16 are multiples of 16)

  // Q fragments in registers (reused across all KV tiles)
  const u16* qbase = qn + ((size_t)bh * 2048 + n0) * 64;
  u16x8 qf[4][2];
#pragma unroll
  for (int mi = 0; mi < 4; mi++)
#pragma unroll
    for (int kk = 0; kk < 2; kk++)
      qf[mi][kk] = *(const u16x8*)(qbase + (wq + mi * 16 + fr) * 64 + kk * 32 + fc);

  f32x4 acc[4][4] = {};
  const u16* kbase = kn + (size_t)bh * 2048 * 64;
  const u16* vbase = vnT + (size_t)bh * 128 * 2048;

  // staging per-lane constants (inverse-swizzled global offsets, u16 units)
  int ks_goff[4];   // K: 4 x 1KB insts/wave; row = wid*32 + i*8 + (lane>>3)
#pragma unroll
  for (int i = 0; i < 4; i++) {
    int row = wid * 32 + i * 8 + (lane >> 3);
    ks_goff[i] = row * 64 + (((lane & 7) ^ (row & 7)) << 3);
  }
  int vs_goff[8];   // V: 8 x 1KB insts/wave; row = wid*32 + i*4 + (lane>>4)
#pragma unroll
  for (int i = 0; i < 8; i++) {
    int row = wid * 32 + i * 4 + (lane >> 4);
    vs_goff[i] = row * 2048 + (((lane & 15) ^ (row & 7)) << 3);
  }

  for (int t = 0; t < 16; t++) {
    const int kv0 = t * 128;
#pragma unroll
    for (int i = 0; i < 4; i++)
      gload_lds16(kbase + (size_t)kv0 * 64 + ks_goff[i], Ks + wid * 2048 + i * 512);
#pragma unroll
    for (int i = 0; i < 8; i++)
      gload_lds16(vbase + (size_t)vs_goff[i] + kv0, Vs + wid * 4096 + i * 512);
    __syncthreads();

    // sim = q @ k^T for this wave's (wq, wc=kv-block)
    f32x4 s[4][4] = {};
#pragma unroll
    for (int kk = 0; kk < 2; kk++) {
      u16x8 kf[4];
#pragma unroll
      for (int ni = 0; ni < 4; ni++) {
        const int row = wc + ni * 16 + fr;
        kf[ni] = *(const u16x8*)(Ks + row * 64 + (((kk * 4 + hi) ^ rb) << 3));
      }
#pragma unroll
      for (int mi = 0; mi < 4; mi++)
#pragma unroll
        for (int ni = 0; ni < 4; ni++)
          s[mi][ni] = mfma16(qf[mi][kk], kf[ni], s[mi][ni]);
    }
    // screen + write P to LDS (swizzled)
#pragma unroll
    for (int mi = 0; mi < 4; mi++)
#pragma unroll
      for (int ni = 0; ni < 4; ni++)
#pragma unroll
        for (int j = 0; j < 4; j++) {
          const int row = wq + mi * 16 + frow + j;
          const int col = wc + ni * 16 + fr;
          float p = fmaxf(0.f, 1.f - r * (1.f - s[mi][ni][j]));
          Ps[row * 128 + (col ^ ((row & 7) << 3))] = f2bf(p * p);
        }
    __syncthreads();

    // PV: acc += P @ V  (wc = this wave's d-block)
#pragma unroll
    for (int kk = 0; kk < 4; kk++) {
      u16x8 pf[4], vf[4];
#pragma unroll
      for (int mi = 0; mi < 4; mi++) {
        const int row = wq + mi * 16 + fr;
        pf[mi] = *(const u16x8*)(Ps + row * 128 + (((kk * 4 + hi) ^ rb) << 3));
      }
#pragma unroll
      for (int ni = 0; ni < 4; ni++) {
        const int row = wc + ni * 16 + fr;
        vf[ni] = *(const u16x8*)(Vs + row * 128 + (((kk * 4 + hi) ^ rb) << 3));
      }
#pragma unroll
      for (int mi = 0; mi < 4; mi++)
#pragma unroll
        for (int ni = 0; ni < 4; ni++)
          acc[mi][ni] = mfma16(pf[mi], vf[ni], acc[mi][ni]);
    }
    __syncthreads();
  }

  // epilogue: tanh_norm(aggr) * gact * exp(ls_hws) -> pre_out[(b*N+n)][h*128+d]
#pragma unroll
  for (int mi = 0; mi < 4; mi++)
#pragma unroll
    for (int j = 0; j < 4; j++) {
      float ss = 0.f;
#pragma unroll
      for (int ni = 0; ni < 4; ni++) { float x = acc[mi][ni][j]; ss += x * x; }
#pragma unroll
      for (int m = 1; m < 16; m <<= 1) ss += __shfl_xor(ss, m);
      if (fr == 0) nbuf[(wid & 1) * 128 + wq + mi * 16 + frow + j] = ss;
    }
  __syncthreads();

  const size_t gbase = ((size_t)bh * 2048 + n0) * 128;
  const size_t obase = ((size_t)(bh >> 4) * 2048 + n0);
#pragma unroll
  for (int mi = 0; mi < 4; mi++)
#pragma unroll
    for (int j = 0; j < 4; j++) {
      const int row = wq + mi * 16 + frow + j;
      float nsq = nbuf[row] + nbuf[128 + row];
      float nn = sqrtf(nsq);
      float scale = tanhf(nn) / fmaxf(nn, 1e-12f) * whs;
#pragma unroll
      for (int ni = 0; ni < 4; ni++) {
        const int d = wc + ni * 16 + fr;
        float gv = bf2f(gact[gbase + (size_t)row * 128 + d]);
        pre_out[(obase + row) * 2048 + h * 128 + d] = f2bf(acc[mi][ni][j] * scale * gv);
      }
    }
}

extern "C" void kernel_launch(void* const* d_in, const int* in_sizes, int n_in,
                              void* d_out, int out_size, void* d_ws, size_t ws_size,
                              hipStream_t stream) {
  (void)in_sizes; (void)n_in; (void)out_size; (void)ws_size;
  const float* tokens = (const float*)d_in[0];
  const float* Wqg = (const float*)d_in[1];
  const float* Wkv = (const float*)d_in[2];
  const float* Wo = (const float*)d_in[3];
  const float* ls_iaw = (const float*)d_in[4];
  const float* ls_hws = (const float*)d_in[5];
  float* out = (float*)d_out;
  char* ws = (char*)d_ws;

  // workspace layout (phased aliasing, total 104 MB):
  u16* WoT = (u16*)(ws + 0);                     // 8,388,608 B
  char* regA = ws + 8388608;                     // 50,331,648 B
  u16* tok_bf = (u16*)(regA);                    // phase A-B
  u16* WqgT = (u16*)(regA + 16777216);
  u16* WkvT = (u16*)(regA + 29360128);
  u16* qn = (u16*)(regA);                        // phase C-D
  u16* kn = (u16*)(regA + 8388608);
  u16* vnT = (u16*)(regA + 16777216);
  u16* gact = (u16*)(regA + 33554432);
  char* regB = ws + 58720256;                    // 50,331,648 B
  u16* qg_raw = (u16*)(regB);                    // phase B-C
  u16* kv_raw = (u16*)(regB + 25165824);
  u16* pre_out = (u16*)(regB);                   // phase D-E

  k_cvt<<<4096, 256, 0, stream>>>(tokens, tok_bf, 8388608);
  k_cvtT<<<dim3(96, 64), 256, 0, stream>>>(Wqg, WqgT, 2048, 3072);
  k_cvtT<<<dim3(96, 64), 256, 0, stream>>>(Wkv, WkvT, 2048, 3072);
  k_cvtT<<<dim3(64, 64), 256, 0, stream>>>(Wo, WoT, 2048, 2048);

  k_gemm<0><<<dim3(24, 32), 256, 0, stream>>>(tok_bf, WqgT, qg_raw, 4096, 3072, 2048);
  k_gemm<0><<<dim3(24, 32), 256, 0, stream>>>(tok_bf, WkvT, kv_raw, 4096, 3072, 2048);

  k_norm<<<16384, 256, 0, stream>>>(qg_raw, kv_raw, qn, kn, vnT, gact);

  k_attn<<<dim3(16, 32), 256, 81920, stream>>>(qn, kn, vnT, gact, ls_iaw, ls_hws, pre_out);

  k_gemm<1><<<dim3(16, 32), 256, 0, stream>>>(pre_out, WoT, out, 4096, 2048, 2048);
}